// Round 6
// baseline (479.926 us; speedup 1.0000x reference)
//
#include <hip/hip_runtime.h>
#include <hip/hip_bf16.h>

#define NC     80
#define BATCH  1048576
#define CHUNKS (BATCH / 32)          // 32768 K-chunks of 32 rows (10240 B each, contiguous)
#define NBLK   512
#define NTHR   128                   // 2 waves/block
#define NWAVES (NBLK * NTHR / 64)    // 1024 waves -> 32 chunks/wave, exact cover
#define NTILE  15                    // upper-triangle 16x16 tiles of 80x80
#define CHUNK_BYTES 10240
#define CHUNK_FLOATS 2560

using bf16x8 = __attribute__((ext_vector_type(8))) __bf16;
using f32x4  = __attribute__((ext_vector_type(4))) float;

// Session ledger:
//  R0/R4 (508.8us): v[8][5] register staging baseline.
//  R1 (528.7us): partial-buffer + reduce      -> REGRESSED (atomics are cheap).
//  R2 (527.5us): pairwise + bounds(,4)        -> REGRESSED (serialized loads).
//  R3 (665.8us): loss fusion                  -> REGRESSED (VGPR 72 alloc,
//                 latency-bound; but gave direct gram measurement 360us).
//  R5 (479.0us): global_load_lds DMA staging, 2-deep, vmcnt(10)  -> WIN -30us.
//  R6 (this): 3-deep pipeline. Theory: under congested-HBM latency L, the
//     2-deep recurrence P = (C+L)/2 binds before HBM BW does (per-wave
//     window only 10-20KB). Depth 3 -> P = (C+L)/3, window 1.5x. This is the
//     DISCRIMINATING experiment between "gram ~170us (latency-window-bound)"
//     and "gram ~60us (at floor, residual is harness poison fills)".
//     LDS: 2 waves x 3 x 10240 B = 61440 B (static <64K); Gs ALIASES the
//     stage buffers (dead after K-loop), zeroed in the epilogue.

#define WAITV20 asm volatile("s_waitcnt vmcnt(20)" ::: "memory")
#define WAITV10 asm volatile("s_waitcnt vmcnt(10)" ::: "memory")
#define WAITV0  asm volatile("s_waitcnt vmcnt(0)"  ::: "memory")
#define WAITLG  asm volatile("s_waitcnt lgkmcnt(0)" ::: "memory")

__device__ __forceinline__ void gload16(const void* g, void* l) {
    // direct global->LDS DMA, 16 B/lane; LDS dest = uniform base + lane*16
    __builtin_amdgcn_global_load_lds(
        (__attribute__((address_space(1))) void*)g,
        (__attribute__((address_space(3))) void*)l,
        16, 0, 0);
}

// issue 10 wave-loads covering one contiguous 10240 B chunk
__device__ __forceinline__ void stage_chunk(const float* __restrict__ label,
                                            int cidx, float* lbuf, int lane) {
    const char* g = (const char*)label + (size_t)cidx * CHUNK_BYTES + lane * 16;
#pragma unroll
    for (int w = 0; w < 10; ++w)
        gload16(g + w * 1024, lbuf + w * 256);
}

// build 5 bf16 fragments from the LDS chunk and do the 15 upper-tri MFMAs.
// lane reads L[(quad*8+j)*80 + t*16 + m]  (same data/frag order as R0 -> exact)
__device__ __forceinline__ void compute_chunk(const float* L, f32x4* acc,
                                              int quad, int m) {
    const float* base = L + quad * 8 * NC + m;
    bf16x8 frag[5];
#pragma unroll
    for (int t = 0; t < 5; ++t) {
        union { unsigned int u[4]; bf16x8 b; } cv;
#pragma unroll
        for (int p = 0; p < 4; ++p) {
            // fp32 -> bf16 by top-16-bit truncation (exact for 0.0 / 1.0)
            unsigned lo = __float_as_uint(base[(2 * p) * NC + t * 16]) >> 16;
            unsigned hi = __float_as_uint(base[(2 * p + 1) * NC + t * 16]) & 0xFFFF0000u;
            cv.u[p] = hi | lo;
        }
        frag[t] = cv.b;
    }
    int idx = 0;
#pragma unroll
    for (int ti = 0; ti < 5; ++ti)
#pragma unroll
        for (int tj = ti; tj < 5; ++tj) {
            acc[idx] = __builtin_amdgcn_mfma_f32_16x16x32_bf16(
                frag[ti], frag[tj], acc[idx], 0, 0, 0);
            ++idx;
        }
}

__global__ __launch_bounds__(NTHR) void gram_kernel(const float* __restrict__ label,
                                                    float* __restrict__ G) {
    // [wave][depth][floats]; 61440 B. Gs (15*256 floats) aliases the front
    // of this array in the epilogue (stage buffers are dead by then).
    __shared__ float smem[2][3][CHUNK_FLOATS];

    const int tid  = threadIdx.x;
    const int lane = tid & 63;
    const int wv   = tid >> 6;               // wave within block (0..1)
    const int m    = lane & 15;              // class-within-tile
    const int quad = lane >> 4;              // k-subchunk selector
    const int wid  = blockIdx.x * 2 + wv;    // global wave id (0..1023)

    float* Ba = &smem[wv][0][0];
    float* Bb = &smem[wv][1][0];
    float* Bc = &smem[wv][2][0];

    // prologue: three chunks in flight (30 loads outstanding)
    stage_chunk(label, wid,              Ba, lane);
    stage_chunk(label, wid + NWAVES,     Bb, lane);
    stage_chunk(label, wid + 2 * NWAVES, Bc, lane);

    f32x4 acc[NTILE];
#pragma unroll
    for (int t = 0; t < NTILE; ++t) acc[t] = (f32x4){0.f, 0.f, 0.f, 0.f};

    // chunk c lives in buf[c%3]; rotation keeps that invariant with zero
    // runtime indexing (rule #20: no scratch).
    const int n = CHUNKS / NWAVES;           // 32
    for (int j = 0; j < n - 3; ++j) {
        WAITV20;                             // chunk j landed; j+1, j+2 in flight
        compute_chunk(Ba, acc, quad, m);
        WAITLG;                              // ds_reads done before DMA overwrite
        stage_chunk(label, wid + (j + 3) * NWAVES, Ba, lane);
        float* t = Ba; Ba = Bb; Bb = Bc; Bc = t;
    }
    WAITV20; compute_chunk(Ba, acc, quad, m);    // chunk n-3
    WAITV10; compute_chunk(Bb, acc, quad, m);    // chunk n-2
    WAITV0;  compute_chunk(Bc, acc, quad, m);    // chunk n-1

    __syncthreads();   // all waves done with stage buffers -> safe to alias

    // Gs = compact 15-tile accumulator, aliased over the stage memory
    float* Gs = &smem[0][0][0];
    for (int u = tid; u < NTILE * 256; u += NTHR) Gs[u] = 0.0f;
    __syncthreads();

    // wave accs -> LDS (C/D layout: col = lane&15, row = quad*4 + reg)
    {
        int idx = 0;
#pragma unroll
        for (int ti = 0; ti < 5; ++ti)
#pragma unroll
            for (int tj = ti; tj < 5; ++tj) {
#pragma unroll
                for (int r = 0; r < 4; ++r)
                    atomicAdd(&Gs[idx * 256 + (quad * 4 + r) * 16 + m], acc[idx][r]);
                ++idx;
            }
    }
    __syncthreads();

    // block partial -> global (R1 lesson: direct atomics beat partial buffers)
    {
        static const unsigned char TI[NTILE] = {0,0,0,0,0,1,1,1,1,2,2,2,3,3,4};
        static const unsigned char TJ[NTILE] = {0,1,2,3,4,1,2,3,4,2,3,4,3,4,4};
#pragma unroll
        for (int idx = 0; idx < NTILE; ++idx) {
            for (int e = tid; e < 256; e += NTHR) {
                int row = 16 * TI[idx] + (e >> 4);
                int col = 16 * TJ[idx] + (e & 15);
                atomicAdd(&G[row * NC + col], Gs[idx * 256 + e]);
            }
        }
    }
}

// Stage 2: target = cooc/(count+eps) + eye ; smooth-L1-ish ; mean -> out[0]
__global__ __launch_bounds__(256) void loss_kernel(const float* __restrict__ pre_adj,
                                                   const float* __restrict__ G,
                                                   float* __restrict__ out) {
    const int tid = threadIdx.x;
    float sum = 0.f;
    for (int u = tid; u < NC * NC; u += 256) {
        int i = u / NC, j = u - i * NC;
        float target;
        if (i == j) {
            target = 1.0f;
        } else {
            // G stored only for tile(i) <= tile(j); G is symmetric
            float num = ((i >> 4) <= (j >> 4)) ? G[i * NC + j] : G[j * NC + i];
            float cnt = G[i * NC + i];            // count[i] = diag (binary labels)
            target = num / (cnt + 1e-7f);
        }
        float r = fabsf(pre_adj[u] - target);
        sum += (r < 1.0f) ? r * r : (r - 0.5f);
    }
    // wave reduce (64 lanes) then cross-wave via LDS
#pragma unroll
    for (int off = 32; off > 0; off >>= 1) sum += __shfl_down(sum, off);
    __shared__ float ws[4];
    if ((tid & 63) == 0) ws[tid >> 6] = sum;
    __syncthreads();
    if (tid == 0) out[0] = (ws[0] + ws[1] + ws[2] + ws[3]) * (1.0f / 6400.0f);
}

extern "C" void kernel_launch(void* const* d_in, const int* in_sizes, int n_in,
                              void* d_out, int out_size, void* d_ws, size_t ws_size,
                              hipStream_t stream) {
    const float* pre_adj = (const float*)d_in[0];   // [80,80]
    const float* label   = (const float*)d_in[1];   // [1048576,80]
    float* out = (float*)d_out;                     // scalar
    float* G   = (float*)d_ws;                      // 80*80 fp32 accumulator

    hipMemsetAsync(G, 0, NC * NC * sizeof(float), stream);
    gram_kernel<<<NBLK, NTHR, 0, stream>>>(label, G);
    loss_kernel<<<1, 256, 0, stream>>>(pre_adj, G, out);
}